// Round 9
// baseline (155.163 us; speedup 1.0000x reference)
//
#include <hip/hip_runtime.h>
#include <math.h>

#define SPIN 365
#define TRAIN 1000000
#define WARM 64
#define TPW 512                     // output rows per wave (tile)
#define BLK 512                     // threads per block (8 waves)
#define WPB (BLK / 64)              // waves per block
#define XROWS (TPW + WARM)          // staged rows per wave = 576
#define XSEG (2 * XROWS + XROWS / 16)   // 1188 floats per wave
#define CSEG (64 * 9)               // c_pre floats per wave (stride 9)
#define NPART 256

// ---------------- obsstd partial reduction (double precision) ----------------

__global__ void partial_std_kernel(const float* __restrict__ y, double* __restrict__ part) {
    int tid = blockIdx.x * blockDim.x + threadIdx.x;
    int stride = gridDim.x * blockDim.x;
    double s = 0.0, s2 = 0.0;
    for (int i = SPIN + tid; i < TRAIN; i += stride) {
        double v = (double)y[i];
        s += v;
        s2 += v * v;
    }
    for (int off = 32; off > 0; off >>= 1) {
        s  += __shfl_down(s,  off, 64);
        s2 += __shfl_down(s2, off, 64);
    }
    __shared__ double ls[4], ls2[4];
    int lane = threadIdx.x & 63, w = threadIdx.x >> 6;
    if (lane == 0) { ls[w] = s; ls2[w] = s2; }
    __syncthreads();
    if (threadIdx.x == 0) {
        double ts = 0.0, ts2 = 0.0;
        int nw = blockDim.x >> 6;
        for (int i = 0; i < nw; ++i) { ts += ls[i]; ts2 += ls2[i]; }
        part[2 * blockIdx.x]     = ts;
        part[2 * blockIdx.x + 1] = ts2;
    }
}

// ---------------- main chunk-parallel scan (wave-autonomous, barrier-free) ----

struct Par { float oo1, ol1, ez1, ez0; };

// State update only: olc*c = c>0 ? min(ol1*c, u2) : ol1*c (identical, rcp-free).
__device__ __forceinline__ void step_state(float& c, float u1, float u2, const Par p) {
    float e   = __builtin_amdgcn_exp2f(fmaf(c, p.ez1, p.ez0));  // exp(-z)
    float sg  = __builtin_amdgcn_rcpf(1.0f + e);                // sigmoid(z)
    float ooc = p.oo1 * sg * c;
    float lc  = p.ol1 * c;
    float mlc = (c > 0.0f) ? fminf(lc, u2) : lc;
    c = c - ooc - mlc + u1;
}

// Full gates for Phase B (reference formulation per-output).
__device__ __forceinline__ void gates(float c, float u2, const Par p,
                                      float& oo, float& olc, float& f) {
    float e  = __builtin_amdgcn_exp2f(fmaf(c, p.ez1, p.ez0));
    float sg = __builtin_amdgcn_rcpf(1.0f + e);
    oo = p.oo1 * sg;
    float rc = __builtin_amdgcn_rcpf(c);
    float q  = u2 * rc;
    float olc_pos = fminf(p.ol1, q);
    olc = (c > 0.0f) ? olc_pos : p.ol1;
    f = 1.0f - oo - olc;
}

// Wave-local LDS x layout: interleaved (u1,u2), +1 dword pad per 16 rows.
__device__ __forceinline__ void ldu(const float* __restrict__ up, int off,
                                    float& a, float& b) {
    int idx = 2 * off + (off >> 4);
    a = up[idx];
    b = up[idx + 1];
}

__global__ __launch_bounds__(BLK, 4)
void scan_kernel(const float* __restrict__ x,
                 const int*  __restrict__ time_lag_p,
                 const float* __restrict__ cm, const float* __restrict__ cs,
                 const float* __restrict__ wro, const float* __restrict__ wrl,
                 const float* __restrict__ wrf, const float* __restrict__ b0p,
                 const float* __restrict__ wb1p,
                 const double* __restrict__ part,
                 float* __restrict__ out, int Btot) {
    __shared__ float s_x[WPB * XSEG];   // 38016 B
    __shared__ float s_c[WPB * CSEG];   // 18432 B
    // NO __syncthreads: all LDS traffic is wave-local (DS ops are in program
    // order within a wave, so a wave's ds_reads see its earlier ds_writes).

    const long long Bl = (long long)Btot;
    const int tl   = time_lag_p[0];
    const int tid  = threadIdx.x;
    const int wid  = tid >> 6;
    const int lane = tid & 63;

    // rows b < time_lag: all outputs zero (no-op when tl == 0)
    if (tl > 0) {
        long long gstride = (long long)gridDim.x * BLK;
        for (long long b = (long long)blockIdx.x * BLK + tid; b < tl; b += gstride) {
            for (int s = 0; s < 10; ++s) out[(long long)s * Bl + b] = 0.0f;
            out[10 * Bl + 2 * b]     = 0.0f;
            out[10 * Bl + 2 * b + 1] = 0.0f;
            out[12 * Bl + b] = 0.0f;
        }
    }

    const long long gw = (long long)blockIdx.x * WPB + wid;   // global wave id
    const long long r0 = (long long)tl + gw * TPW;            // wave's first output row
    if (r0 >= Bl) return;                                     // whole wave exits

    // uniform scalars
    const float wo = wro[0], wl = wrl[0], wf = wrf[0];
    const float b0 = b0p[0], wb1 = wb1p[0], mo = cm[0], so = cs[0];
    const float eo = __expf(wo), el = __expf(wl), ef = __expf(wf);
    const float denom = eo + el + ef;
    const float kz1 = wb1 / so;
    const float kz0 = b0 - mo * kz1;
    const float LOG2E = 1.4426950408889634f;
    Par par;
    par.oo1 = eo / denom;
    par.ol1 = el / denom;
    par.ez1 = -kz1 * LOG2E;
    par.ez0 = -kz0 * LOG2E;
    const float ol1 = par.ol1;

    // per-wave obsstd final reduction (4 KB, L2-hot)
    double s = 0.0, s2 = 0.0;
    for (int i = lane; i < NPART; i += 64) {
        s  += part[2 * i];
        s2 += part[2 * i + 1];
    }
    for (int off = 32; off > 0; off >>= 1) {
        s  += __shfl_down(s,  off, 64);
        s2 += __shfl_down(s2, off, 64);
    }
    s  = __shfl(s, 0, 64);
    s2 = __shfl(s2, 0, 64);
    const double nn = (double)(TRAIN - SPIN);
    const float ostd = (float)sqrt((s2 - s * s / nn) / (nn - 1.0));

    const bool aligned = ((tl & 3) == 0);
    const float4 z4  = make_float4(0.0f, 0.0f, 0.0f, 0.0f);
    const float4 ol4 = make_float4(ol1, ol1, ol1, ol1);
    const float4 os4 = make_float4(ostd, ostd, ostd, ostd);

    // ---- pre-issue input-independent output streams (4,5,7,12) NOW ----
    // Starts the HBM write drain ~7 us before Phase B; these streams are
    // NOT written again in B's aligned path (each byte written once).
    if (aligned) {
        #pragma unroll
        for (int h = 0; h < 2; ++h) {
            const long long r = r0 + h * 256 + lane * 4;
            if (r + 3 < Bl) {
                *(float4*)(out + 4 * Bl + r)  = z4;
                *(float4*)(out + 5 * Bl + r)  = z4;
                *(float4*)(out + 7 * Bl + r)  = ol4;
                *(float4*)(out + 12 * Bl + r) = os4;
            }
        }
    }

    const long long base    = r0 - WARM;        // first staged row (may be < tl)
    const long long lastrow = Bl - 1;
    float* sx = s_x + wid * XSEG;
    float* sc = s_c + wid * CSEG;

    // ---- stage this wave's x window [r0-WARM, r0+TPW) into its LDS segment ----
    #pragma unroll
    for (int k = 0; k < XROWS / 64; ++k) {      // 9 coalesced float2 loads
        int off = k * 64 + lane;
        long long row = base + off;
        row = row < 0 ? 0 : (row > lastrow ? lastrow : row);
        float2 v = *(const float2*)(x + 2 * row);
        int idx = 2 * off + (off >> 4);
        sx[idx]     = v.x;
        sx[idx + 1] = v.y;
    }

    // ---- Phase A: per-thread recurrence (8 rows), c_pre -> wave LDS ----
    {
        const long long rt = r0 + (long long)lane * 8;
        if (rt < Bl) {
            long long wstart = rt - WARM;
            if (wstart < tl) wstart = tl;
            const int nwarm = (int)(rt - wstart);
            long long lenl = Bl - rt;
            const int len = lenl > 8 ? 8 : (int)lenl;
            const int off0 = (int)(wstart - base);

            float c = 0.0f;                     // exact when clamped to tl
            float aA[8], bA[8], aB[8], bB[8];

            if (nwarm == WARM) {                // common path
                #pragma unroll
                for (int q = 0; q < 8; ++q) ldu(sx, off0 + q, aA[q], bA[q]);
                #pragma unroll
                for (int g = 0; g < 4; ++g) {   // 64 warm steps, ping-pong
                    #pragma unroll
                    for (int q = 0; q < 8; ++q) ldu(sx, off0 + (2 * g + 1) * 8 + q, aB[q], bB[q]);
                    #pragma unroll
                    for (int q = 0; q < 8; ++q) step_state(c, aA[q], bA[q], par);
                    #pragma unroll
                    for (int q = 0; q < 8; ++q) ldu(sx, off0 + (2 * g + 2) * 8 + q, aA[q], bA[q]);
                    #pragma unroll
                    for (int q = 0; q < 8; ++q) step_state(c, aB[q], bB[q], par);
                }
                // aA/bA now hold the 8 output rows
            } else {                            // first 8 lanes of tile 0 only
                for (int t = 0; t < nwarm; ++t) {
                    float ua, ub;
                    ldu(sx, off0 + t, ua, ub);
                    step_state(c, ua, ub, par);
                }
                #pragma unroll
                for (int q = 0; q < 8; ++q) ldu(sx, off0 + nwarm + q, aA[q], bA[q]);
            }

            float* my = sc + lane * 9;
            #pragma unroll
            for (int j = 0; j < 8; ++j) {
                if (j < len) my[j] = c;         // pre-update state
                step_state(c, aA[j], bA[j], par);
            }
        }
    }

    // ---- Phase B: re-derive gates from wave-local c_pre, coalesced stores ----
    #pragma unroll
    for (int h = 0; h < 2; ++h) {
        const int rl = h * 256 + lane * 4;      // local row (multiple of 4)
        const long long r = r0 + rl;
        if (r >= Bl) continue;

        const int sidx = rl >> 3;               // producer lane (same wave)
        const int j0   = (lane & 1) * 4;        // element offset within producer
        float cp[4], u2v[4];
        #pragma unroll
        for (int e = 0; e < 4; ++e) {
            cp[e] = sc[sidx * 9 + j0 + e];
            float ua, ub;
            ldu(sx, WARM + rl + e, ua, ub);
            u2v[e] = ub;
        }

        if (aligned && (r + 3 < Bl)) {
            float h4[4], lo[4], lc[4], go[4], gc[4], gf[4];
            #pragma unroll
            for (int e = 0; e < 4; ++e) {
                float oo, olc, f;
                gates(cp[e], u2v[e], par, oo, olc, f);
                h4[e] = oo * cp[e];
                lo[e] = ol1 * cp[e];
                lc[e] = olc * cp[e];
                go[e] = oo;
                gc[e] = olc;
                gf[e] = f;
            }
            // streams 4,5,7,12 already written in the pre-issue pass
            *(float4*)(out + r)          = make_float4(h4[0], h4[1], h4[2], h4[3]);
            *(float4*)(out + Bl + r)     = make_float4(cp[0], cp[1], cp[2], cp[3]);
            *(float4*)(out + 2 * Bl + r) = make_float4(lo[0], lo[1], lo[2], lo[3]);
            *(float4*)(out + 3 * Bl + r) = make_float4(lc[0], lc[1], lc[2], lc[3]);
            *(float4*)(out + 6 * Bl + r) = make_float4(go[0], go[1], go[2], go[3]);
            *(float4*)(out + 8 * Bl + r) = make_float4(gc[0], gc[1], gc[2], gc[3]);
            *(float4*)(out + 9 * Bl + r) = make_float4(gf[0], gf[1], gf[2], gf[3]);
            *(float4*)(out + 10 * Bl + 2 * r)     = make_float4(h4[0], ostd, h4[1], ostd);
            *(float4*)(out + 10 * Bl + 2 * r + 4) = make_float4(h4[2], ostd, h4[3], ostd);
        } else {
            #pragma unroll
            for (int e = 0; e < 4; ++e) {
                long long t = r + e;
                if (t >= Bl) break;
                float oo, olc, f;
                gates(cp[e], u2v[e], par, oo, olc, f);
                float hh = oo * cp[e];
                out[t]           = hh;
                out[Bl + t]      = cp[e];
                out[2 * Bl + t]  = ol1 * cp[e];
                out[3 * Bl + t]  = olc * cp[e];
                out[4 * Bl + t]  = 0.0f;
                out[5 * Bl + t]  = 0.0f;
                out[6 * Bl + t]  = oo;
                out[7 * Bl + t]  = ol1;
                out[8 * Bl + t]  = olc;
                out[9 * Bl + t]  = f;
                out[10 * Bl + 2 * t]     = hh;
                out[10 * Bl + 2 * t + 1] = ostd;
                out[12 * Bl + t] = ostd;
            }
        }
    }
}

// ---------------- host launch ----------------

extern "C" void kernel_launch(void* const* d_in, const int* in_sizes, int n_in,
                              void* d_out, int out_size, void* d_ws, size_t ws_size,
                              hipStream_t stream) {
    const float* x        = (const float*)d_in[0];
    // d_in[1] = epoch (unused)
    const int*   time_lag = (const int*)d_in[2];
    const float* y_obs    = (const float*)d_in[3];
    const float* c_mean   = (const float*)d_in[4];
    const float* c_std    = (const float*)d_in[5];
    const float* w_yom    = (const float*)d_in[6];
    const float* w_ylm    = (const float*)d_in[7];
    const float* w_yfm    = (const float*)d_in[8];
    const float* b0       = (const float*)d_in[9];
    const float* wb1      = (const float*)d_in[10];
    float* out = (float*)d_out;

    const int B = in_sizes[0] / 2;   // SEQ=1, IN=2

    double* part = (double*)d_ws;

    partial_std_kernel<<<NPART, 256, 0, stream>>>(y_obs, part);

    // one 512-row tile per wave; worst case tl=0 -> ceil(B/512) tiles
    const long long ntiles = ((long long)B + TPW - 1) / TPW;
    const int blocks = (int)((ntiles + WPB - 1) / WPB);      // 489 for B = 2e6
    scan_kernel<<<blocks, BLK, 0, stream>>>(x, time_lag, c_mean, c_std,
                                            w_yom, w_ylm, w_yfm, b0, wb1,
                                            part, out, B);
}

// Round 10
// 150.534 us; speedup vs baseline: 1.0307x; 1.0307x over previous
//
#include <hip/hip_runtime.h>
#include <math.h>

#define SPIN 365
#define TRAIN 1000000
#define WARM 64
#define TPW 512                     // output rows per wave (tile)
#define BLK 512                     // threads per block (8 waves)
#define WPB (BLK / 64)              // waves per block
#define XROWS (TPW + WARM)          // staged rows per wave = 576
#define XSEG (2 * XROWS + XROWS / 16)   // 1188 floats per wave
#define CSEG (64 * 9)               // c_pre floats per wave (stride 9)
#define NPART 256

// ---------------- obsstd partial reduction (double precision) ----------------

__global__ void partial_std_kernel(const float* __restrict__ y, double* __restrict__ part) {
    int tid = blockIdx.x * blockDim.x + threadIdx.x;
    int stride = gridDim.x * blockDim.x;
    double s = 0.0, s2 = 0.0;
    for (int i = SPIN + tid; i < TRAIN; i += stride) {
        double v = (double)y[i];
        s += v;
        s2 += v * v;
    }
    for (int off = 32; off > 0; off >>= 1) {
        s  += __shfl_down(s,  off, 64);
        s2 += __shfl_down(s2, off, 64);
    }
    __shared__ double ls[4], ls2[4];
    int lane = threadIdx.x & 63, w = threadIdx.x >> 6;
    if (lane == 0) { ls[w] = s; ls2[w] = s2; }
    __syncthreads();
    if (threadIdx.x == 0) {
        double ts = 0.0, ts2 = 0.0;
        int nw = blockDim.x >> 6;
        for (int i = 0; i < nw; ++i) { ts += ls[i]; ts2 += ls2[i]; }
        part[2 * blockIdx.x]     = ts;
        part[2 * blockIdx.x + 1] = ts2;
    }
}

// ---------------- main chunk-parallel scan (wave-autonomous, barrier-free) ----

struct Par { float oo1, ol1, ez1, ez0; };

// State update only: olc*c = c>0 ? min(ol1*c, u2) : ol1*c (identical, rcp-free).
__device__ __forceinline__ void step_state(float& c, float u1, float u2, const Par p) {
    float e   = __builtin_amdgcn_exp2f(fmaf(c, p.ez1, p.ez0));  // exp(-z)
    float sg  = __builtin_amdgcn_rcpf(1.0f + e);                // sigmoid(z)
    float ooc = p.oo1 * sg * c;
    float lc  = p.ol1 * c;
    float mlc = (c > 0.0f) ? fminf(lc, u2) : lc;
    c = c - ooc - mlc + u1;
}

// Full gates for Phase B (reference formulation per-output).
__device__ __forceinline__ void gates(float c, float u2, const Par p,
                                      float& oo, float& olc, float& f) {
    float e  = __builtin_amdgcn_exp2f(fmaf(c, p.ez1, p.ez0));
    float sg = __builtin_amdgcn_rcpf(1.0f + e);
    oo = p.oo1 * sg;
    float rc = __builtin_amdgcn_rcpf(c);
    float q  = u2 * rc;
    float olc_pos = fminf(p.ol1, q);
    olc = (c > 0.0f) ? olc_pos : p.ol1;
    f = 1.0f - oo - olc;
}

// Wave-local LDS x layout: interleaved (u1,u2), +1 dword pad per 16 rows.
__device__ __forceinline__ void ldu(const float* __restrict__ up, int off,
                                    float& a, float& b) {
    int idx = 2 * off + (off >> 4);
    a = up[idx];
    b = up[idx + 1];
}

__global__ __launch_bounds__(BLK, 4)
void scan_kernel(const float* __restrict__ x,
                 const int*  __restrict__ time_lag_p,
                 const float* __restrict__ cm, const float* __restrict__ cs,
                 const float* __restrict__ wro, const float* __restrict__ wrl,
                 const float* __restrict__ wrf, const float* __restrict__ b0p,
                 const float* __restrict__ wb1p,
                 const double* __restrict__ part,
                 float* __restrict__ out, int Btot) {
    __shared__ float s_x[WPB * XSEG];   // 38016 B
    __shared__ float s_c[WPB * CSEG];   // 18432 B
    // NO __syncthreads: all LDS traffic is wave-local (DS ops are in program
    // order within a wave, so a wave's ds_reads see its earlier ds_writes).

    const long long Bl = (long long)Btot;
    const int tl   = time_lag_p[0];
    const int tid  = threadIdx.x;
    const int wid  = tid >> 6;
    const int lane = tid & 63;

    // rows b < time_lag: all outputs zero (no-op when tl == 0)
    if (tl > 0) {
        long long gstride = (long long)gridDim.x * BLK;
        for (long long b = (long long)blockIdx.x * BLK + tid; b < tl; b += gstride) {
            for (int s = 0; s < 10; ++s) out[(long long)s * Bl + b] = 0.0f;
            out[10 * Bl + 2 * b]     = 0.0f;
            out[10 * Bl + 2 * b + 1] = 0.0f;
            out[12 * Bl + b] = 0.0f;
        }
    }

    const long long gw = (long long)blockIdx.x * WPB + wid;   // global wave id
    const long long r0 = (long long)tl + gw * TPW;            // wave's first output row
    if (r0 >= Bl) return;                                     // whole wave exits

    // uniform scalars
    const float wo = wro[0], wl = wrl[0], wf = wrf[0];
    const float b0 = b0p[0], wb1 = wb1p[0], mo = cm[0], so = cs[0];
    const float eo = __expf(wo), el = __expf(wl), ef = __expf(wf);
    const float denom = eo + el + ef;
    const float kz1 = wb1 / so;
    const float kz0 = b0 - mo * kz1;
    const float LOG2E = 1.4426950408889634f;
    Par par;
    par.oo1 = eo / denom;
    par.ol1 = el / denom;
    par.ez1 = -kz1 * LOG2E;
    par.ez0 = -kz0 * LOG2E;
    const float ol1 = par.ol1;

    // per-wave obsstd final reduction (4 KB, L2-hot)
    double s = 0.0, s2 = 0.0;
    for (int i = lane; i < NPART; i += 64) {
        s  += part[2 * i];
        s2 += part[2 * i + 1];
    }
    for (int off = 32; off > 0; off >>= 1) {
        s  += __shfl_down(s,  off, 64);
        s2 += __shfl_down(s2, off, 64);
    }
    s  = __shfl(s, 0, 64);
    s2 = __shfl(s2, 0, 64);
    const double nn = (double)(TRAIN - SPIN);
    const float ostd = (float)sqrt((s2 - s * s / nn) / (nn - 1.0));

    const long long base    = r0 - WARM;        // first staged row (may be < tl)
    const long long lastrow = Bl - 1;
    float* sx = s_x + wid * XSEG;
    float* sc = s_c + wid * CSEG;

    // ---- stage this wave's x window [r0-WARM, r0+TPW) into its LDS segment ----
    #pragma unroll
    for (int k = 0; k < XROWS / 64; ++k) {      // 9 coalesced float2 loads
        int off = k * 64 + lane;
        long long row = base + off;
        row = row < 0 ? 0 : (row > lastrow ? lastrow : row);
        float2 v = *(const float2*)(x + 2 * row);
        int idx = 2 * off + (off >> 4);
        sx[idx]     = v.x;
        sx[idx + 1] = v.y;
    }

    // ---- Phase A: per-thread recurrence (8 rows), c_pre -> wave LDS ----
    {
        const long long rt = r0 + (long long)lane * 8;
        if (rt < Bl) {
            long long wstart = rt - WARM;
            if (wstart < tl) wstart = tl;
            const int nwarm = (int)(rt - wstart);
            long long lenl = Bl - rt;
            const int len = lenl > 8 ? 8 : (int)lenl;
            const int off0 = (int)(wstart - base);

            float c = 0.0f;                     // exact when clamped to tl
            float aA[8], bA[8], aB[8], bB[8];

            if (nwarm == WARM) {                // common path
                #pragma unroll
                for (int q = 0; q < 8; ++q) ldu(sx, off0 + q, aA[q], bA[q]);
                #pragma unroll
                for (int g = 0; g < 4; ++g) {   // 64 warm steps, ping-pong
                    #pragma unroll
                    for (int q = 0; q < 8; ++q) ldu(sx, off0 + (2 * g + 1) * 8 + q, aB[q], bB[q]);
                    #pragma unroll
                    for (int q = 0; q < 8; ++q) step_state(c, aA[q], bA[q], par);
                    #pragma unroll
                    for (int q = 0; q < 8; ++q) ldu(sx, off0 + (2 * g + 2) * 8 + q, aA[q], bA[q]);
                    #pragma unroll
                    for (int q = 0; q < 8; ++q) step_state(c, aB[q], bB[q], par);
                }
                // aA/bA now hold the 8 output rows
            } else {                            // first 8 lanes of tile 0 only
                for (int t = 0; t < nwarm; ++t) {
                    float ua, ub;
                    ldu(sx, off0 + t, ua, ub);
                    step_state(c, ua, ub, par);
                }
                #pragma unroll
                for (int q = 0; q < 8; ++q) ldu(sx, off0 + nwarm + q, aA[q], bA[q]);
            }

            float* my = sc + lane * 9;
            #pragma unroll
            for (int j = 0; j < 8; ++j) {
                if (j < len) my[j] = c;         // pre-update state
                step_state(c, aA[j], bA[j], par);
            }
        }
    }

    // ---- Phase B: re-derive gates from wave-local c_pre, coalesced stores ----
    const bool aligned = ((tl & 3) == 0);
    const float4 z4  = make_float4(0.0f, 0.0f, 0.0f, 0.0f);
    const float4 ol4 = make_float4(ol1, ol1, ol1, ol1);
    const float4 os4 = make_float4(ostd, ostd, ostd, ostd);

    #pragma unroll
    for (int h = 0; h < 2; ++h) {
        const int rl = h * 256 + lane * 4;      // local row (multiple of 4)
        const long long r = r0 + rl;
        if (r >= Bl) continue;

        const int sidx = rl >> 3;               // producer lane (same wave)
        const int j0   = (lane & 1) * 4;        // element offset within producer
        float cp[4], u2v[4];
        #pragma unroll
        for (int e = 0; e < 4; ++e) {
            cp[e] = sc[sidx * 9 + j0 + e];
            float ua, ub;
            ldu(sx, WARM + rl + e, ua, ub);
            u2v[e] = ub;
        }

        if (aligned && (r + 3 < Bl)) {
            float h4[4], lo[4], lc[4], go[4], gc[4], gf[4];
            #pragma unroll
            for (int e = 0; e < 4; ++e) {
                float oo, olc, f;
                gates(cp[e], u2v[e], par, oo, olc, f);
                h4[e] = oo * cp[e];
                lo[e] = ol1 * cp[e];
                lc[e] = olc * cp[e];
                go[e] = oo;
                gc[e] = olc;
                gf[e] = f;
            }
            *(float4*)(out + r)          = make_float4(h4[0], h4[1], h4[2], h4[3]);
            *(float4*)(out + Bl + r)     = make_float4(cp[0], cp[1], cp[2], cp[3]);
            *(float4*)(out + 2 * Bl + r) = make_float4(lo[0], lo[1], lo[2], lo[3]);
            *(float4*)(out + 3 * Bl + r) = make_float4(lc[0], lc[1], lc[2], lc[3]);
            *(float4*)(out + 4 * Bl + r) = z4;
            *(float4*)(out + 5 * Bl + r) = z4;
            *(float4*)(out + 6 * Bl + r) = make_float4(go[0], go[1], go[2], go[3]);
            *(float4*)(out + 7 * Bl + r) = ol4;
            *(float4*)(out + 8 * Bl + r) = make_float4(gc[0], gc[1], gc[2], gc[3]);
            *(float4*)(out + 9 * Bl + r) = make_float4(gf[0], gf[1], gf[2], gf[3]);
            *(float4*)(out + 10 * Bl + 2 * r)     = make_float4(h4[0], ostd, h4[1], ostd);
            *(float4*)(out + 10 * Bl + 2 * r + 4) = make_float4(h4[2], ostd, h4[3], ostd);
            *(float4*)(out + 12 * Bl + r) = os4;
        } else {
            #pragma unroll
            for (int e = 0; e < 4; ++e) {
                long long t = r + e;
                if (t >= Bl) break;
                float oo, olc, f;
                gates(cp[e], u2v[e], par, oo, olc, f);
                float hh = oo * cp[e];
                out[t]           = hh;
                out[Bl + t]      = cp[e];
                out[2 * Bl + t]  = ol1 * cp[e];
                out[3 * Bl + t]  = olc * cp[e];
                out[4 * Bl + t]  = 0.0f;
                out[5 * Bl + t]  = 0.0f;
                out[6 * Bl + t]  = oo;
                out[7 * Bl + t]  = ol1;
                out[8 * Bl + t]  = olc;
                out[9 * Bl + t]  = f;
                out[10 * Bl + 2 * t]     = hh;
                out[10 * Bl + 2 * t + 1] = ostd;
                out[12 * Bl + t] = ostd;
            }
        }
    }
}

// ---------------- host launch ----------------

extern "C" void kernel_launch(void* const* d_in, const int* in_sizes, int n_in,
                              void* d_out, int out_size, void* d_ws, size_t ws_size,
                              hipStream_t stream) {
    const float* x        = (const float*)d_in[0];
    // d_in[1] = epoch (unused)
    const int*   time_lag = (const int*)d_in[2];
    const float* y_obs    = (const float*)d_in[3];
    const float* c_mean   = (const float*)d_in[4];
    const float* c_std    = (const float*)d_in[5];
    const float* w_yom    = (const float*)d_in[6];
    const float* w_ylm    = (const float*)d_in[7];
    const float* w_yfm    = (const float*)d_in[8];
    const float* b0       = (const float*)d_in[9];
    const float* wb1      = (const float*)d_in[10];
    float* out = (float*)d_out;

    const int B = in_sizes[0] / 2;   // SEQ=1, IN=2

    double* part = (double*)d_ws;

    partial_std_kernel<<<NPART, 256, 0, stream>>>(y_obs, part);

    // one 512-row tile per wave; worst case tl=0 -> ceil(B/512) tiles
    const long long ntiles = ((long long)B + TPW - 1) / TPW;
    const int blocks = (int)((ntiles + WPB - 1) / WPB);      // 489 for B = 2e6
    scan_kernel<<<blocks, BLK, 0, stream>>>(x, time_lag, c_mean, c_std,
                                            w_yom, w_ylm, w_yfm, b0, wb1,
                                            part, out, B);
}